// Round 10
// baseline (187.133 us; speedup 1.0000x reference)
//
#include <hip/hip_runtime.h>
#include <hip/hip_bf16.h>
#include <math.h>

typedef unsigned short ushort_t;
typedef __attribute__((ext_vector_type(8))) unsigned short ushort8;
typedef __attribute__((ext_vector_type(8))) __bf16 bf16x8;
typedef __attribute__((ext_vector_type(4))) float f32x4;

__device__ inline ushort_t f2b(float f) {
  __hip_bfloat16 h = __float2bfloat16(f);
  return __builtin_bit_cast(ushort_t, h);
}
__device__ inline float b2f(ushort_t u) {
  __hip_bfloat16 h = __builtin_bit_cast(__hip_bfloat16, u);
  return __bfloat162float(h);
}

__device__ inline void gload16(const ushort_t* g, ushort_t* l) {
  __builtin_amdgcn_global_load_lds(
      (const __attribute__((address_space(1))) unsigned int*)g,
      (__attribute__((address_space(3))) unsigned int*)l, 16, 0, 0);
}

// bijective XCD swizzle (m204)
__device__ inline void xcd_swz(int& bx, int& by, int& bz) {
  const int nx = gridDim.x, ny = gridDim.y;
  const int nwg = nx * ny * gridDim.z;
  const int orig = blockIdx.x + nx * (blockIdx.y + ny * blockIdx.z);
  const int q = nwg >> 3, r = nwg & 7, xcd = orig & 7, loc = orig >> 3;
  const int wg = (xcd < r ? xcd * (q + 1) : r * (q + 1) + (xcd - r) * q) + loc;
  bx = wg % nx;
  by = (wg / nx) % ny;
  bz = wg / (nx * ny);
}

// ---------------- weights fp32 -> bf16 ----------------
__global__ __launch_bounds__(256) void prep_weights(
    const float* __restrict__ qkv_w, const float* __restrict__ proj_w,
    ushort_t* __restrict__ qkvw, ushort_t* __restrict__ projw) {
  int idx = blockIdx.x * 256 + threadIdx.x;
  const int NQ = 1536 * 512;
  if (idx < NQ) {
    qkvw[idx] = f2b(qkv_w[idx]);
  } else {
    int j = idx - NQ;
    if (j < 512 * 512) projw[j] = f2b(proj_w[j]);
  }
}

// ---------------- GN stats ----------------
__global__ __launch_bounds__(256) void gn_stats(const float* __restrict__ x,
                                                float* __restrict__ stats) {
  const int tid = threadIdx.x;
  const int bg = blockIdx.x;
  const float4* xv = (const float4*)(x + (size_t)bg * 65536);
  float s = 0.f, ss = 0.f;
  for (int i = tid; i < 16384; i += 256) {
    float4 v = xv[i];
    s += v.x + v.y + v.z + v.w;
    ss += v.x * v.x + v.y * v.y + v.z * v.z + v.w * v.w;
  }
  __shared__ float red[8];
  for (int off = 32; off > 0; off >>= 1) {
    s += __shfl_down(s, off);
    ss += __shfl_down(ss, off);
  }
  if ((tid & 63) == 0) { red[tid >> 6] = s; red[4 + (tid >> 6)] = ss; }
  __syncthreads();
  if (tid == 0) {
    float st = red[0] + red[1] + red[2] + red[3];
    float sst = red[4] + red[5] + red[6] + red[7];
    float mean = st * (1.f / 65536.f);
    float var = sst * (1.f / 65536.f) - mean * mean;
    stats[bg * 2] = mean;
    stats[bg * 2 + 1] = rsqrtf(var + 1e-6f);
  }
}

// ---------------- GN apply + transpose ----------------
__global__ __launch_bounds__(256) void gn_apply_t(
    const float* __restrict__ x, const float* __restrict__ w,
    const float* __restrict__ bgn, const float* __restrict__ stats,
    ushort_t* __restrict__ xnT) {
  __shared__ ushort_t tile[64][68];
  const int b = blockIdx.z;
  const int p0 = blockIdx.x * 64, c0 = blockIdx.y * 64;
  const int tid = threadIdx.x;
  const float* xb = x + ((size_t)b * 512 + c0) * 4096 + p0;
  const int tc = tid >> 4, tp = (tid & 15) * 4;
#pragma unroll
  for (int pass = 0; pass < 4; ++pass) {
    int c = pass * 16 + tc;
    int cg = c0 + c;
    float mean = stats[(b * 32 + (cg >> 4)) * 2];
    float inv = stats[(b * 32 + (cg >> 4)) * 2 + 1];
    float wc = w[cg] * inv;
    float bc = bgn[cg] - mean * wc;
    float4 v = *(const float4*)(xb + (size_t)c * 4096 + tp);
    tile[c][tp] = f2b(v.x * wc + bc);
    tile[c][tp + 1] = f2b(v.y * wc + bc);
    tile[c][tp + 2] = f2b(v.z * wc + bc);
    tile[c][tp + 3] = f2b(v.w * wc + bc);
  }
  __syncthreads();
  const int c8 = (tid & 7) * 8;
#pragma unroll
  for (int pass = 0; pass < 2; ++pass) {
    int p = pass * 32 + (tid >> 3);
    ushort8 u;
#pragma unroll
    for (int e = 0; e < 8; ++e) u[e] = tile[c8 + e][p];
    *(ushort8*)(xnT + ((size_t)b * 4096 + p0 + p) * 512 + c0 + c8) = u;
  }
}

// ====== 128x128 pipelined bf16 GEMM (BK=64, counted vmcnt, swizzled) ======
// C[m][n] = sum_k A[m][k]*B[n][k];  K = per-split contraction length
// EPI: 0 bf16 +bias[n]; 3 bf16 *colsc[n]; 5 plain bf16 (split partials);
//      7 P = exp(v*scale) + column sums (QK^T), LDS-vectorized store
template <int EPI, int SPLIT>
__global__ __launch_bounds__(256, 2) void gemm_pl(
    const ushort_t* __restrict__ A, const ushort_t* __restrict__ B,
    void* __restrict__ Cg, const float* __restrict__ bias,
    const float* __restrict__ colsc, float* __restrict__ smp, int N, int K,
    int lda, int ldb, size_t sA, size_t sB, size_t sC, size_t sSp,
    float scale) {
  __shared__ __align__(16) ushort_t Al[2][128 * 64];  // 16KB x2
  __shared__ __align__(16) ushort_t Bl[2][128 * 64];
  __shared__ float s_red[2][128];
  int bx, by, bzt;
  xcd_swz(bx, by, bzt);
  const int bz = bzt / SPLIT, sp = bzt % SPLIT;
  const ushort_t* Ab = A + bz * sA + (size_t)sp * K;
  const ushort_t* Bb = B + bz * sB + (size_t)sp * K;
  const int bm0 = by * 128, bn0 = bx * 128;
  const int tid = threadIdx.x;
  const int w = tid >> 6, lane = tid & 63;
  const int wm = (w >> 1) * 64, wn = (w & 1) * 64;
  const int fr = lane & 15, fq = lane >> 4;

  const int srow = tid >> 3, scb = tid & 7;
  const int ssw = scb ^ (srow & 7);
  const ushort_t* aS = Ab + (size_t)(bm0 + srow) * lda + ssw * 8;
  const ushort_t* bS = Bb + (size_t)(bn0 + srow) * ldb + ssw * 8;

  auto stage = [&](int s, int kk) {
#pragma unroll
    for (int g = 0; g < 4; ++g)
      gload16(aS + (size_t)(g * 32) * lda + kk, &Al[s][g * 2048 + w * 512]);
#pragma unroll
    for (int g = 0; g < 4; ++g)
      gload16(bS + (size_t)(g * 32) * ldb + kk, &Bl[s][g * 2048 + w * 512]);
  };

  f32x4 acc[4][4] = {};
  bf16x8 a_r[4][2], b_r[4][2];

  const int nt = K >> 6;
  stage(0, 0);
  if (nt > 1) {
    stage(1, 64);
    asm volatile("s_waitcnt vmcnt(8)" ::: "memory");
  } else {
    asm volatile("s_waitcnt vmcnt(0)" ::: "memory");
  }
  __builtin_amdgcn_s_barrier();

  for (int t = 0; t < nt; ++t) {
    const int s = t & 1;
#pragma unroll
    for (int mi = 0; mi < 4; ++mi) {
      int row = wm + mi * 16 + fr;
#pragma unroll
      for (int ks = 0; ks < 2; ++ks) {
        int blk = ((ks * 4 + fq) ^ (row & 7)) * 8;
        a_r[mi][ks] = *(const bf16x8*)&Al[s][row * 64 + blk];
      }
    }
#pragma unroll
    for (int ni = 0; ni < 4; ++ni) {
      int row = wn + ni * 16 + fr;
#pragma unroll
      for (int ks = 0; ks < 2; ++ks) {
        int blk = ((ks * 4 + fq) ^ (row & 7)) * 8;
        b_r[ni][ks] = *(const bf16x8*)&Bl[s][row * 64 + blk];
      }
    }
    __builtin_amdgcn_s_barrier();
    __builtin_amdgcn_s_setprio(1);
#pragma unroll
    for (int ks = 0; ks < 2; ++ks)
#pragma unroll
      for (int mi = 0; mi < 4; ++mi)
#pragma unroll
        for (int ni = 0; ni < 2; ++ni)
          acc[mi][ni] = __builtin_amdgcn_mfma_f32_16x16x32_bf16(
              a_r[mi][ks], b_r[ni][ks], acc[mi][ni], 0, 0, 0);
    __builtin_amdgcn_s_setprio(0);
    __builtin_amdgcn_s_barrier();  // all waves done reading slot s
    if (t + 2 < nt) stage(s, (t + 2) << 6);
    __builtin_amdgcn_s_setprio(1);
#pragma unroll
    for (int ks = 0; ks < 2; ++ks)
#pragma unroll
      for (int mi = 0; mi < 4; ++mi)
#pragma unroll
        for (int ni = 2; ni < 4; ++ni)
          acc[mi][ni] = __builtin_amdgcn_mfma_f32_16x16x32_bf16(
              a_r[mi][ks], b_r[ni][ks], acc[mi][ni], 0, 0, 0);
    __builtin_amdgcn_s_setprio(0);
    if (t + 2 < nt)
      asm volatile("s_waitcnt vmcnt(8)" ::: "memory");
    else if (t + 1 < nt)
      asm volatile("s_waitcnt vmcnt(0)" ::: "memory");
    __builtin_amdgcn_s_barrier();
  }

  const int r0 = fq * 4;
  const size_t cbase = (size_t)sp * sSp + (size_t)bz * sC;

  if constexpr (EPI == 7) {
    // exp + per-column sums + LDS-transposed vectorized store.
    // Al (32 KB contiguous) is free after the loop-end barrier.
    ushort_t* tp = &Al[0][0];  // [128 rows][128 cols], XOR(row&15) swizzle
    float csum[4] = {0.f, 0.f, 0.f, 0.f};
#pragma unroll
    for (int mi = 0; mi < 4; ++mi)
#pragma unroll
      for (int r = 0; r < 4; ++r) {
        int lr = wm + mi * 16 + r0 + r;
#pragma unroll
        for (int ni = 0; ni < 4; ++ni) {
          int col = wn + ni * 16 + fr;
          float e = __expf(fminf(acc[mi][ni][r] * scale, 76.f));
          csum[ni] += e;
          int cb = col >> 3;
          tp[lr * 128 + (((cb ^ (lr & 15)) << 3) | (col & 7))] = f2b(e);
        }
      }
    __syncthreads();
#pragma unroll
    for (int i = 0; i < 8; ++i) {
      int b16 = tid * 8 + i;
      int row = b16 >> 4, cb = b16 & 15;
      ushort8 u = *(const ushort8*)&tp[row * 128 + ((cb ^ (row & 15)) << 3)];
      size_t off = cbase + (size_t)(bm0 + row) * N + bn0 + cb * 8;
      *(ushort8*)((ushort_t*)Cg + off) = u;
    }
    // column-sum partial for this 128-row chunk
#pragma unroll
    for (int ni = 0; ni < 4; ++ni) {
      float s = csum[ni];
      s += __shfl_xor(s, 16);
      s += __shfl_xor(s, 32);
      if (lane < 16) s_red[w >> 1][wn + ni * 16 + lane] = s;
    }
    __syncthreads();
    if (tid < 128)
      smp[((size_t)bz * 32 + by) * 4096 + bn0 + tid] =
          s_red[0][tid] + s_red[1][tid];
    return;
  }

#pragma unroll
  for (int mi = 0; mi < 4; mi++) {
#pragma unroll
    for (int r = 0; r < 4; r++) {
      int gm = bm0 + wm + mi * 16 + r0 + r;
#pragma unroll
      for (int ni = 0; ni < 4; ni++) {
        int gn = bn0 + wn + ni * 16 + fr;
        float v = acc[mi][ni][r];
        size_t off = cbase + (size_t)gm * N + gn;
        if constexpr (EPI == 0) {
          ((ushort_t*)Cg)[off] = f2b(v + bias[gn]);
        } else if constexpr (EPI == 3) {
          ((ushort_t*)Cg)[off] = f2b(v * colsc[(size_t)bz * 4096 + gn]);
        } else {
          ((ushort_t*)Cg)[off] = f2b(v);
        }
      }
    }
  }
}

// -------- softmax finalize: alpha_j = 1/S_j from 32 sum-partials --------
__global__ __launch_bounds__(256) void sm_fin(const float* __restrict__ part,
                                              float* __restrict__ alpha) {
  int idx = blockIdx.x * 256 + threadIdx.x;  // b*4096 + j
  int b = idx >> 12, j = idx & 4095;
  float S = 0.f;
#pragma unroll
  for (int rc = 0; rc < 32; rc++)
    S += part[((size_t)b * 32 + rc) * 4096 + j];
  alpha[idx] = 1.f / S;
}

// -- finalize: out[b][o][p] = part0[b][p][o] + part1[b][p][o] + x + proj_b --
__global__ __launch_bounds__(256) void finalize(
    const ushort_t* __restrict__ part, const float* __restrict__ x,
    const float* __restrict__ pb, float* __restrict__ out) {
  __shared__ float tile[64][68];
  const int b = blockIdx.z;
  const int p0 = blockIdx.x * 64, o0 = blockIdx.y * 64;
  const int tid = threadIdx.x;
  const int tp = tid >> 2, to = (tid & 3) * 16;
  const size_t base = ((size_t)b * 4096 + p0 + tp) * 512 + o0 + to;
  ushort8 u0 = *(const ushort8*)(part + base);
  ushort8 u1 = *(const ushort8*)(part + base + 8);
  ushort8 v0 = *(const ushort8*)(part + 4194304 + base);
  ushort8 v1 = *(const ushort8*)(part + 4194304 + base + 8);
#pragma unroll
  for (int e = 0; e < 8; ++e) {
    tile[tp][to + e] = b2f(u0[e]) + b2f(v0[e]);
    tile[tp][to + 8 + e] = b2f(u1[e]) + b2f(v1[e]);
  }
  __syncthreads();
  const int wo = tid >> 2, wp = (tid & 3) * 16;
  float bias = pb[o0 + wo];
  const float* xr = x + ((size_t)b * 512 + o0 + wo) * 4096 + p0 + wp;
  float* orow = out + ((size_t)b * 512 + o0 + wo) * 4096 + p0 + wp;
#pragma unroll
  for (int e = 0; e < 16; ++e)
    orow[e] = tile[wp + e][wo] + xr[e] + bias;
}

extern "C" void kernel_launch(void* const* d_in, const int* in_sizes, int n_in,
                              void* d_out, int out_size, void* d_ws,
                              size_t ws_size, hipStream_t stream) {
  const float* x = (const float*)d_in[0];
  const float* gn_w = (const float*)d_in[1];
  const float* gn_b = (const float*)d_in[2];
  const float* qkv_w = (const float*)d_in[3];
  const float* qkv_b = (const float*)d_in[4];
  const float* proj_w = (const float*)d_in[5];
  const float* proj_b = (const float*)d_in[6];
  float* out = (float*)d_out;

  char* ws = (char*)d_ws;
  ushort_t* xnT   = (ushort_t*)(ws);              //  8 MB [p][c] (dead after QKV)
  ushort_t* Wpp   = (ushort_t*)(ws);              //  reuse: W''[b][o][j] 8 MB
  ushort_t* qkvw  = (ushort_t*)(ws + 8388608);
  ushort_t* projw = (ushort_t*)(ws + 9961472);
  float*    stats = (float*)(ws + 10485760);
  ushort_t* qkvT  = (ushort_t*)(ws + 10486272);   // 25 MB [p][1536] (dead after W'')
  ushort_t* part  = (ushort_t*)(ws + 10486272);   // reuse: 2x8 MB split partials
  ushort_t* P     = (ushort_t*)(ws + 35652096);   // 64 MB [io][j] = exp(L)
  float*    smp   = (float*)(ws + 102760960);     //  1 MB (32 sum-partials/col)
  float*    alpha = (float*)(ws + 104858112);     //  32 KB

  const float scale = 0.04419417382415922f;  // 1/sqrt(512)
  const size_t sXN = 2097152, sQKV = (size_t)4096 * 1536, sP = 16777216;

  prep_weights<<<4096, 256, 0, stream>>>(qkv_w, proj_w, qkvw, projw);
  gn_stats<<<64, 256, 0, stream>>>(x, stats);
  gn_apply_t<<<dim3(64, 8, 2), 256, 0, stream>>>(x, gn_w, gn_b, stats, xnT);
  // qkvT[p][o] = sum_c xnT[p][c]*qkvw[o][c] + qkv_b[o]  (M=8192 both batches)
  gemm_pl<0, 1><<<dim3(12, 64, 1), 256, 0, stream>>>(
      xnT, qkvw, qkvT, qkv_b, nullptr, nullptr, 1536, 512, 512, 512, 0, 0, 0,
      0, 1.f);
  // P[io][j] = exp(scale * qT[io].kT[j]) ; fused column sums (32 chunks)
  gemm_pl<7, 1><<<dim3(32, 32, 2), 256, 0, stream>>>(
      qkvT, qkvT + 512, P, nullptr, nullptr, smp, 4096, 512, 1536, 1536, sQKV,
      sQKV, sP, 0, scale);
  sm_fin<<<32, 256, 0, stream>>>(smp, alpha);
  // W''[o][j] = alpha_j * sum_c projw[o][c]*vT[j][c]
  gemm_pl<3, 1><<<dim3(32, 4, 2), 256, 0, stream>>>(
      projw, qkvT + 1024, Wpp, nullptr, alpha, nullptr, 4096, 512, 512, 1536,
      0, sQKV, sXN, 0, 1.f);
  // part[sp][b][p][o] = sum_{j in half sp} P[p][j]*W''[o][j]  (split-K=2)
  gemm_pl<5, 2><<<dim3(4, 32, 4), 256, 0, stream>>>(
      P, Wpp, part, nullptr, nullptr, nullptr, 512, 2048, 4096, 4096, sP, sXN,
      sXN, 4194304, 1.f);
  // out[o][p] = part0 + part1 + x + proj_b[o]
  finalize<<<dim3(64, 8, 2), 256, 0, stream>>>(part, x, proj_b, out);
}

// Round 11
// 171.678 us; speedup vs baseline: 1.0900x; 1.0900x over previous
//
#include <hip/hip_runtime.h>
#include <hip/hip_bf16.h>
#include <math.h>

typedef unsigned short ushort_t;
typedef __attribute__((ext_vector_type(8))) unsigned short ushort8;
typedef __attribute__((ext_vector_type(8))) __bf16 bf16x8;
typedef __attribute__((ext_vector_type(4))) float f32x4;

__device__ inline ushort_t f2b(float f) {
  __hip_bfloat16 h = __float2bfloat16(f);
  return __builtin_bit_cast(ushort_t, h);
}
__device__ inline float b2f(ushort_t u) {
  __hip_bfloat16 h = __builtin_bit_cast(__hip_bfloat16, u);
  return __bfloat162float(h);
}

__device__ inline void gload16(const ushort_t* g, ushort_t* l) {
  __builtin_amdgcn_global_load_lds(
      (const __attribute__((address_space(1))) unsigned int*)g,
      (__attribute__((address_space(3))) unsigned int*)l, 16, 0, 0);
}

// bijective XCD swizzle (m204)
__device__ inline void xcd_swz(int& bx, int& by, int& bz) {
  const int nx = gridDim.x, ny = gridDim.y;
  const int nwg = nx * ny * gridDim.z;
  const int orig = blockIdx.x + nx * (blockIdx.y + ny * blockIdx.z);
  const int q = nwg >> 3, r = nwg & 7, xcd = orig & 7, loc = orig >> 3;
  const int wg = (xcd < r ? xcd * (q + 1) : r * (q + 1) + (xcd - r) * q) + loc;
  bx = wg % nx;
  by = (wg / nx) % ny;
  bz = wg / (nx * ny);
}

// ------- merged: weights fp32->bf16 (blocks 0..4095) + GN stats (4096..4159) -
__global__ __launch_bounds__(256) void prep_stats(
    const float* __restrict__ qkv_w, const float* __restrict__ proj_w,
    const float* __restrict__ x, ushort_t* __restrict__ qkvw,
    ushort_t* __restrict__ projw, float* __restrict__ stats) {
  const int tid = threadIdx.x;
  if (blockIdx.x < 4096) {
    int idx = blockIdx.x * 256 + tid;
    const int NQ = 1536 * 512;
    if (idx < NQ) {
      qkvw[idx] = f2b(qkv_w[idx]);
    } else {
      int j = idx - NQ;
      if (j < 512 * 512) projw[j] = f2b(proj_w[j]);
    }
    return;
  }
  const int bg = blockIdx.x - 4096;  // b*32+g
  const float4* xv = (const float4*)(x + (size_t)bg * 65536);
  float s = 0.f, ss = 0.f;
  for (int i = tid; i < 16384; i += 256) {
    float4 v = xv[i];
    s += v.x + v.y + v.z + v.w;
    ss += v.x * v.x + v.y * v.y + v.z * v.z + v.w * v.w;
  }
  __shared__ float red[8];
  for (int off = 32; off > 0; off >>= 1) {
    s += __shfl_down(s, off);
    ss += __shfl_down(ss, off);
  }
  if ((tid & 63) == 0) { red[tid >> 6] = s; red[4 + (tid >> 6)] = ss; }
  __syncthreads();
  if (tid == 0) {
    float st = red[0] + red[1] + red[2] + red[3];
    float sst = red[4] + red[5] + red[6] + red[7];
    float mean = st * (1.f / 65536.f);
    float var = sst * (1.f / 65536.f) - mean * mean;
    stats[bg * 2] = mean;
    stats[bg * 2 + 1] = rsqrtf(var + 1e-6f);
  }
}

// ---------------- GN apply + transpose ----------------
__global__ __launch_bounds__(256) void gn_apply_t(
    const float* __restrict__ x, const float* __restrict__ w,
    const float* __restrict__ bgn, const float* __restrict__ stats,
    ushort_t* __restrict__ xnT) {
  __shared__ ushort_t tile[64][68];
  const int b = blockIdx.z;
  const int p0 = blockIdx.x * 64, c0 = blockIdx.y * 64;
  const int tid = threadIdx.x;
  const float* xb = x + ((size_t)b * 512 + c0) * 4096 + p0;
  const int tc = tid >> 4, tp = (tid & 15) * 4;
#pragma unroll
  for (int pass = 0; pass < 4; ++pass) {
    int c = pass * 16 + tc;
    int cg = c0 + c;
    float mean = stats[(b * 32 + (cg >> 4)) * 2];
    float inv = stats[(b * 32 + (cg >> 4)) * 2 + 1];
    float wc = w[cg] * inv;
    float bc = bgn[cg] - mean * wc;
    float4 v = *(const float4*)(xb + (size_t)c * 4096 + tp);
    tile[c][tp] = f2b(v.x * wc + bc);
    tile[c][tp + 1] = f2b(v.y * wc + bc);
    tile[c][tp + 2] = f2b(v.z * wc + bc);
    tile[c][tp + 3] = f2b(v.w * wc + bc);
  }
  __syncthreads();
  const int c8 = (tid & 7) * 8;
#pragma unroll
  for (int pass = 0; pass < 2; ++pass) {
    int p = pass * 32 + (tid >> 3);
    ushort8 u;
#pragma unroll
    for (int e = 0; e < 8; ++e) u[e] = tile[c8 + e][p];
    *(ushort8*)(xnT + ((size_t)b * 4096 + p0 + p) * 512 + c0 + c8) = u;
  }
}

// ====== 256x256 8-phase bf16 QK^T GEMM: P = exp(scale*A.B^T), col sums ======
__global__ __launch_bounds__(512, 2) void gemm8(
    const ushort_t* __restrict__ A, const ushort_t* __restrict__ B,
    ushort_t* __restrict__ Cg, float* __restrict__ smp, int N, int K, int lda,
    int ldb, size_t sA, size_t sB, size_t sC, float scale) {
  __shared__ __align__(16) ushort_t smem[66560];
  ushort_t* Asl = smem;          // + s*16384
  ushort_t* Bsl = smem + 32768;  // + s*16384
  float* s_sum = (float*)(smem + 65536);

  int bx, by, bz;
  xcd_swz(bx, by, bz);
  const ushort_t* Ab = A + bz * sA;
  const ushort_t* Bb = B + bz * sB;
  const int bm0 = by * 256, bn0 = bx * 256;
  const int tid = threadIdx.x;
  const int w = tid >> 6, lane = tid & 63;
  const int wr = w >> 2, wc = w & 3;
  const int fr = lane & 15, fq = lane >> 4;

  const int srow = tid >> 3, scb = tid & 7;
  const int ssw = scb ^ (srow & 7);
  const ushort_t* aS = Ab + (size_t)(bm0 + srow) * lda + ssw * 8;
  const ushort_t* bS = Bb + (size_t)(bn0 + srow) * ldb + ssw * 8;

  auto stage_a = [&](int s, int kk) {
#pragma unroll
    for (int g = 0; g < 4; ++g)
      gload16(aS + (size_t)(g * 64) * lda + kk,
              &Asl[s * 16384 + g * 4096 + w * 512]);
  };
  auto stage_b = [&](int s, int kk) {
#pragma unroll
    for (int g = 0; g < 4; ++g)
      gload16(bS + (size_t)(g * 64) * ldb + kk,
              &Bsl[s * 16384 + g * 4096 + w * 512]);
  };

  f32x4 acc[8][4] = {};
  bf16x8 a_r[4][2], b_r[4][2];

  auto read_a = [&](int s, int mh) {
#pragma unroll
    for (int mi = 0; mi < 4; ++mi) {
      int row = wr * 128 + mh * 64 + mi * 16 + fr;
#pragma unroll
      for (int ks = 0; ks < 2; ++ks) {
        int blk = ((ks * 4 + fq) ^ (row & 7)) * 8;
        a_r[mi][ks] = *(const bf16x8*)&Asl[s * 16384 + row * 64 + blk];
      }
    }
  };
  auto read_b = [&](int s, int nh) {
#pragma unroll
    for (int ni = 0; ni < 2; ++ni) {
      int row = wc * 64 + nh * 32 + ni * 16 + fr;
#pragma unroll
      for (int ks = 0; ks < 2; ++ks) {
        int blk = ((ks * 4 + fq) ^ (row & 7)) * 8;
        b_r[nh * 2 + ni][ks] = *(const bf16x8*)&Bsl[s * 16384 + row * 64 + blk];
      }
    }
  };
  auto phase_mfma = [&](int mh, int nh) {
    __builtin_amdgcn_s_setprio(1);
#pragma unroll
    for (int ks = 0; ks < 2; ++ks)
#pragma unroll
      for (int mi = 0; mi < 4; ++mi)
#pragma unroll
        for (int ni = 0; ni < 2; ++ni)
          acc[mh * 4 + mi][nh * 2 + ni] =
              __builtin_amdgcn_mfma_f32_16x16x32_bf16(
                  a_r[mi][ks], b_r[nh * 2 + ni][ks],
                  acc[mh * 4 + mi][nh * 2 + ni], 0, 0, 0);
    __builtin_amdgcn_s_setprio(0);
  };

  const int nt = K >> 6;
  stage_b(0, 0);
  stage_a(0, 0);
  if (nt > 1) {
    stage_b(1, 64);
    stage_a(1, 64);
    asm volatile("s_waitcnt vmcnt(8)" ::: "memory");
  } else {
    asm volatile("s_waitcnt vmcnt(0)" ::: "memory");
  }
  __builtin_amdgcn_s_barrier();

  for (int t = 0; t < nt; ++t) {
    const int s = t & 1;
    const int kk2 = (t + 2) << 6;
    const bool st2 = (t + 2) < nt;
    read_a(s, 0);
    read_b(s, 0);
    __builtin_amdgcn_s_barrier();
    phase_mfma(0, 0);
    __builtin_amdgcn_s_barrier();
    read_b(s, 1);
    __builtin_amdgcn_s_barrier();
    phase_mfma(0, 1);
    __builtin_amdgcn_s_barrier();
    read_a(s, 1);
    asm volatile("" ::: "memory");
    if (st2) stage_b(s, kk2);
    __builtin_amdgcn_s_barrier();
    phase_mfma(1, 0);
    __builtin_amdgcn_s_barrier();
    asm volatile("" ::: "memory");
    if (st2) stage_a(s, kk2);
    __builtin_amdgcn_s_barrier();
    phase_mfma(1, 1);
    if (st2)
      asm volatile("s_waitcnt vmcnt(8)" ::: "memory");
    else if (t + 1 < nt)
      asm volatile("s_waitcnt vmcnt(0)" ::: "memory");
    __builtin_amdgcn_s_barrier();
  }
  __syncthreads();  // all LDS reads drained before transpose reuse

  // ---- epilogue: exp + column sums + LDS-transposed nontemporal store ----
  const size_t cbase = (size_t)bz * sC;
  float csum[4] = {0.f, 0.f, 0.f, 0.f};
  ushort_t* tp = smem;  // 128 rows x 256 ushorts, block-XOR swizzled
#pragma unroll
  for (int step = 0; step < 2; ++step) {
    if (wr == step) {
#pragma unroll
      for (int mi = 0; mi < 8; ++mi)
#pragma unroll
        for (int ni = 0; ni < 4; ++ni)
#pragma unroll
          for (int r = 0; r < 4; ++r) {
            int lr = mi * 16 + fq * 4 + r;
            int col = wc * 64 + ni * 16 + fr;
            float e = __expf(fminf(acc[mi][ni][r] * scale, 76.f));
            csum[ni] += e;
            int cblk = col >> 3;
            tp[lr * 256 + (((cblk ^ (lr & 7)) << 3) | (col & 7))] = f2b(e);
          }
    }
    __syncthreads();
#pragma unroll
    for (int k = 0; k < 8; ++k) {
      int row = (tid >> 5) + 16 * k;
      int cblk = tid & 31;
      ushort8 u = *(const ushort8*)&tp[row * 256 + ((cblk ^ (row & 7)) << 3)];
      size_t off =
          cbase + (size_t)(bm0 + step * 128 + row) * N + bn0 + cblk * 8;
      __builtin_nontemporal_store(u, (ushort8*)(Cg + off));
    }
    __syncthreads();
  }
#pragma unroll
  for (int ni = 0; ni < 4; ++ni) {
    float s = csum[ni];
    s += __shfl_xor(s, 16);
    s += __shfl_xor(s, 32);
    if (lane < 16) s_sum[wr * 256 + wc * 64 + ni * 16 + lane] = s;
  }
  __syncthreads();
  if (tid < 256) {
    smp[((size_t)bz * 16 + by) * 4096 + bn0 + tid] =
        s_sum[tid] + s_sum[256 + tid];
  }
}

// ====== 128x128 pipelined bf16 GEMM (BK=64, counted vmcnt, swizzled) ======
// C[m][n] = sum_k A[m][k]*B[n][k];  K = per-split contraction length
// EPI: 0 bf16 +bias[n]; 3 bf16 *alpha[n] (alpha folded from smp partials);
//      5 plain bf16 nontemporal (split partials)
template <int EPI, int SPLIT>
__global__ __launch_bounds__(256, 2) void gemm_pl(
    const ushort_t* __restrict__ A, const ushort_t* __restrict__ B,
    void* __restrict__ Cg, const float* __restrict__ bias,
    const float* __restrict__ colsc, int N, int K, int lda, int ldb,
    size_t sA, size_t sB, size_t sC, size_t sSp) {
  __shared__ __align__(16) ushort_t Al[2][128 * 64];  // 16KB x2
  __shared__ __align__(16) ushort_t Bl[2][128 * 64];
  __shared__ float s_alpha[128];
  int bx, by, bzt;
  xcd_swz(bx, by, bzt);
  const int bz = bzt / SPLIT, sp = bzt % SPLIT;
  const ushort_t* Ab = A + bz * sA + (size_t)sp * K;
  const ushort_t* Bb = B + bz * sB + (size_t)sp * K;
  const int bm0 = by * 128, bn0 = bx * 128;
  const int tid = threadIdx.x;
  const int w = tid >> 6, lane = tid & 63;
  const int wm = (w >> 1) * 64, wn = (w & 1) * 64;
  const int fr = lane & 15, fq = lane >> 4;

  if constexpr (EPI == 3) {
    // alpha_n = 1/sum of 16 column partials (colsc = smp base)
    if (tid < 128) {
      float S = 0.f;
#pragma unroll
      for (int rc = 0; rc < 16; ++rc)
        S += colsc[((size_t)bz * 16 + rc) * 4096 + bn0 + tid];
      s_alpha[tid] = 1.f / S;
    }
    asm volatile("s_waitcnt lgkmcnt(0)" ::: "memory");
  }

  const int srow = tid >> 3, scb = tid & 7;
  const int ssw = scb ^ (srow & 7);
  const ushort_t* aS = Ab + (size_t)(bm0 + srow) * lda + ssw * 8;
  const ushort_t* bS = Bb + (size_t)(bn0 + srow) * ldb + ssw * 8;

  auto stage = [&](int s, int kk) {
#pragma unroll
    for (int g = 0; g < 4; ++g)
      gload16(aS + (size_t)(g * 32) * lda + kk, &Al[s][g * 2048 + w * 512]);
#pragma unroll
    for (int g = 0; g < 4; ++g)
      gload16(bS + (size_t)(g * 32) * ldb + kk, &Bl[s][g * 2048 + w * 512]);
  };

  f32x4 acc[4][4] = {};
  bf16x8 a_r[4][2], b_r[4][2];

  const int nt = K >> 6;
  stage(0, 0);
  if (nt > 1) {
    stage(1, 64);
    asm volatile("s_waitcnt vmcnt(8)" ::: "memory");
  } else {
    asm volatile("s_waitcnt vmcnt(0)" ::: "memory");
  }
  __builtin_amdgcn_s_barrier();

  for (int t = 0; t < nt; ++t) {
    const int s = t & 1;
#pragma unroll
    for (int mi = 0; mi < 4; ++mi) {
      int row = wm + mi * 16 + fr;
#pragma unroll
      for (int ks = 0; ks < 2; ++ks) {
        int blk = ((ks * 4 + fq) ^ (row & 7)) * 8;
        a_r[mi][ks] = *(const bf16x8*)&Al[s][row * 64 + blk];
      }
    }
#pragma unroll
    for (int ni = 0; ni < 4; ++ni) {
      int row = wn + ni * 16 + fr;
#pragma unroll
      for (int ks = 0; ks < 2; ++ks) {
        int blk = ((ks * 4 + fq) ^ (row & 7)) * 8;
        b_r[ni][ks] = *(const bf16x8*)&Bl[s][row * 64 + blk];
      }
    }
    __builtin_amdgcn_s_barrier();
    __builtin_amdgcn_s_setprio(1);
#pragma unroll
    for (int ks = 0; ks < 2; ++ks)
#pragma unroll
      for (int mi = 0; mi < 4; ++mi)
#pragma unroll
        for (int ni = 0; ni < 2; ++ni)
          acc[mi][ni] = __builtin_amdgcn_mfma_f32_16x16x32_bf16(
              a_r[mi][ks], b_r[ni][ks], acc[mi][ni], 0, 0, 0);
    __builtin_amdgcn_s_setprio(0);
    __builtin_amdgcn_s_barrier();  // all waves done reading slot s
    if (t + 2 < nt) stage(s, (t + 2) << 6);
    __builtin_amdgcn_s_setprio(1);
#pragma unroll
    for (int ks = 0; ks < 2; ++ks)
#pragma unroll
      for (int mi = 0; mi < 4; ++mi)
#pragma unroll
        for (int ni = 2; ni < 4; ++ni)
          acc[mi][ni] = __builtin_amdgcn_mfma_f32_16x16x32_bf16(
              a_r[mi][ks], b_r[ni][ks], acc[mi][ni], 0, 0, 0);
    __builtin_amdgcn_s_setprio(0);
    if (t + 2 < nt)
      asm volatile("s_waitcnt vmcnt(8)" ::: "memory");
    else if (t + 1 < nt)
      asm volatile("s_waitcnt vmcnt(0)" ::: "memory");
    __builtin_amdgcn_s_barrier();
  }

  const int r0 = (lane >> 4) * 4;
  const size_t cbase = (size_t)sp * sSp + (size_t)bz * sC;
#pragma unroll
  for (int mi = 0; mi < 4; mi++) {
#pragma unroll
    for (int r = 0; r < 4; r++) {
      int gm = bm0 + wm + mi * 16 + r0 + r;
#pragma unroll
      for (int ni = 0; ni < 4; ni++) {
        int gn = bn0 + wn + ni * 16 + fr;
        float v = acc[mi][ni][r];
        size_t off = cbase + (size_t)gm * N + gn;
        if constexpr (EPI == 0) {
          ((ushort_t*)Cg)[off] = f2b(v + bias[gn]);
        } else if constexpr (EPI == 3) {
          ((ushort_t*)Cg)[off] = f2b(v * s_alpha[gn - bn0]);
        } else {
          __builtin_nontemporal_store(f2b(v), (ushort_t*)Cg + off);
        }
      }
    }
  }
}

// -- finalize: out[b][o][p] = part0[b][p][o] + part1[b][p][o] + x + proj_b --
__global__ __launch_bounds__(256) void finalize(
    const ushort_t* __restrict__ part, const float* __restrict__ x,
    const float* __restrict__ pb, float* __restrict__ out) {
  __shared__ float tile[64][68];
  const int b = blockIdx.z;
  const int p0 = blockIdx.x * 64, o0 = blockIdx.y * 64;
  const int tid = threadIdx.x;
  const int tp = tid >> 2, to = (tid & 3) * 16;
  const size_t base = ((size_t)b * 4096 + p0 + tp) * 512 + o0 + to;
  ushort8 u0 = *(const ushort8*)(part + base);
  ushort8 u1 = *(const ushort8*)(part + base + 8);
  ushort8 v0 = *(const ushort8*)(part + 4194304 + base);
  ushort8 v1 = *(const ushort8*)(part + 4194304 + base + 8);
#pragma unroll
  for (int e = 0; e < 8; ++e) {
    tile[tp][to + e] = b2f(u0[e]) + b2f(v0[e]);
    tile[tp][to + 8 + e] = b2f(u1[e]) + b2f(v1[e]);
  }
  __syncthreads();
  const int wo = tid >> 2, wp = (tid & 3) * 16;
  float bias = pb[o0 + wo];
  const float* xr = x + ((size_t)b * 512 + o0 + wo) * 4096 + p0 + wp;
  float* orow = out + ((size_t)b * 512 + o0 + wo) * 4096 + p0 + wp;
#pragma unroll
  for (int e = 0; e < 16; ++e)
    orow[e] = tile[wp + e][wo] + xr[e] + bias;
}

extern "C" void kernel_launch(void* const* d_in, const int* in_sizes, int n_in,
                              void* d_out, int out_size, void* d_ws,
                              size_t ws_size, hipStream_t stream) {
  const float* x = (const float*)d_in[0];
  const float* gn_w = (const float*)d_in[1];
  const float* gn_b = (const float*)d_in[2];
  const float* qkv_w = (const float*)d_in[3];
  const float* qkv_b = (const float*)d_in[4];
  const float* proj_w = (const float*)d_in[5];
  const float* proj_b = (const float*)d_in[6];
  float* out = (float*)d_out;

  char* ws = (char*)d_ws;
  ushort_t* xnT   = (ushort_t*)(ws);              //  8 MB [p][c] (dead after QKV)
  ushort_t* Wpp   = (ushort_t*)(ws);              //  reuse: W''[b][o][j] 8 MB
  ushort_t* qkvw  = (ushort_t*)(ws + 8388608);
  ushort_t* projw = (ushort_t*)(ws + 9961472);
  float*    stats = (float*)(ws + 10485760);
  ushort_t* qkvT  = (ushort_t*)(ws + 10486272);   // 25 MB [p][1536] (dead after W'')
  ushort_t* part  = (ushort_t*)(ws + 10486272);   // reuse: 2x8 MB split partials
  ushort_t* P     = (ushort_t*)(ws + 35652096);   // 64 MB [io][j] = exp(L)
  float*    smp   = (float*)(ws + 102760960);     //  0.5 MB (16 sum-partials/col)

  const float scale = 0.04419417382415922f;  // 1/sqrt(512)
  const size_t sXN = 2097152, sQKV = (size_t)4096 * 1536, sP = 16777216;

  prep_stats<<<4160, 256, 0, stream>>>(qkv_w, proj_w, x, qkvw, projw, stats);
  gn_apply_t<<<dim3(64, 8, 2), 256, 0, stream>>>(x, gn_w, gn_b, stats, xnT);
  // qkvT[p][o] = sum_c xnT[p][c]*qkvw[o][c] + qkv_b[o]  (M=8192 both batches)
  gemm_pl<0, 1><<<dim3(12, 64, 1), 256, 0, stream>>>(
      xnT, qkvw, qkvT, qkv_b, nullptr, 1536, 512, 512, 512, 0, 0, 0, 0);
  // P[io][j] = exp(scale * qT[io].kT[j]) ; fused column sums (16 chunks)
  gemm8<<<dim3(16, 16, 2), 512, 0, stream>>>(
      qkvT, qkvT + 512, P, smp, 4096, 512, 1536, 1536, sQKV, sQKV, sP, scale);
  // W''[o][j] = alpha_j * sum_c projw[o][c]*vT[j][c]  (alpha folded from smp)
  gemm_pl<3, 1><<<dim3(32, 4, 2), 256, 0, stream>>>(
      projw, qkvT + 1024, Wpp, nullptr, smp, 4096, 512, 512, 1536, 0, sQKV,
      sXN, 0);
  // part[sp][b][p][o] = sum_{j in half sp} P[p][j]*W''[o][j]  (split-K=2)
  gemm_pl<5, 2><<<dim3(4, 32, 4), 256, 0, stream>>>(
      P, Wpp, part, nullptr, nullptr, 512, 2048, 4096, 4096, sP, sXN, sXN,
      4194304);
  // out[o][p] = part0 + part1 + x + proj_b[o]
  finalize<<<dim3(64, 8, 2), 256, 0, stream>>>(part, x, proj_b, out);
}